// Round 4
// baseline (111.937 us; speedup 1.0000x reference)
//
#include <hip/hip_runtime.h>

#define FRAME 160
#define ORDER 12
#define NFRAMES (4096 * 15)
#define EPL 10            // elements per lane (16 lanes per frame)
#define FPW 4             // frames per wave
#define PADF 12           // zero front-pad per frame row (FIR history)
#define ROWL (PADF + FRAME)

template<int CTRL>
__device__ __forceinline__ float dppf(float v) {
    return __int_as_float(__builtin_amdgcn_update_dpp(
        0, __float_as_int(v), CTRL, 0xF, 0xF, true));
}

// Sum across each 16-lane row, pure-VALU DPP; bit-identical in all 16 lanes.
__device__ __forceinline__ float rowsum16(float v) {
    v += dppf<0xB1>(v);    // quad_perm [1,0,3,2]  : lane ^= 1
    v += dppf<0x4E>(v);    // quad_perm [2,3,0,1]  : lane ^= 2
    v += dppf<0x140>(v);   // row_mirror
    v += dppf<0x141>(v);   // row_half_mirror
    return v;
}

__global__ __launch_bounds__(256) void ResidualEmbedding_70798240907390_kernel(
    const int* __restrict__ bits, const float* __restrict__ pcm,
    const float* __restrict__ alpha_p, float* __restrict__ out)
{
    const int tid  = threadIdx.x;
    const int wave = tid >> 6;
    const int lane = tid & 63;
    const int g    = lane >> 4;
    const int s    = lane & 15;
    const int wf0  = (blockIdx.x * 4 + wave) * FPW;
    const int f_id = wf0 + g;

    __shared__ float s_win[161];                  // Hann + win[160]=0 pad
    __shared__ float s_x[4][FPW * ROWL + 1];      // 12-zero front pad per frame
    __shared__ float s_a[4][FPW][16];

    // Window: once per block. win[160]=0 kills the lane15 forward edge case.
    if (tid < 161) {
        float w = (tid < 160)
            ? 0.5f - 0.5f * __cosf(6.2831853071795864769f / 159.0f * (float)tid)
            : 0.0f;
        s_win[tid] = w;
    }
    // Zero pads: 4 frames x 12 front zeros + 1 tail element per wave.
    if (lane < FPW * PADF) {
        int fr = lane / PADF, sl = lane % PADF;
        s_x[wave][fr * ROWL + sl] = 0.0f;
    }
    if (lane == 63) s_x[wave][FPW * ROWL] = 0.0f;
    // Stage 4 frames (160 float4/wave), 16B-aligned dst (688g + 48 bytes).
    {
        const float4* src = (const float4*)(pcm + (size_t)wf0 * FRAME);
#pragma unroll
        for (int it = 0; it < 3; ++it) {
            int id = lane + 64 * it;              // 0..191
            if (id < 160) {
                int fr = id / 40, ix = id % 40;
                *(float4*)&s_x[wave][fr * ROWL + PADF + 4 * ix] = src[fr * 40 + ix];
            }
        }
    }
    __syncthreads();

    const float* Xr = &s_x[wave][g * ROWL];       // Xr[PADF + n] = x[n]
    const int p0 = s * EPL;

    // prod[j] = x[p0+j]*win[p0+j]; b[p]=prod[p], f[p]=prod[p+1].
    float pr[EPL + 1];
#pragma unroll
    for (int j = 0; j <= EPL; ++j)
        pr[j] = Xr[PADF + p0 + j] * s_win[p0 + j];

    float F[EPL], B[EPL];
#pragma unroll
    for (int t = 0; t < EPL; ++t) { F[t] = pr[t + 1]; B[t] = pr[t]; }
    B[EPL - 1] = (s == 15) ? 0.0f : B[EPL - 1];   // position 159 invalid for b
    float dp0 = 0.0f, dp1 = 0.0f;
#pragma unroll
    for (int t = 0; t < EPL; ++t) {
        dp0 = fmaf(F[t], F[t], dp0);
        dp1 = fmaf(B[t], B[t], dp1);
    }
    float den = rowsum16(dp0 + dp1);

    // a (lane s holds a[s]) and pivot-reversal ar[s] = a[i+1-s].
    float a  = (s == 0) ? 1.0f : 0.0f;
    float ar = (s == 1) ? 1.0f : 0.0f;
    float cpart = 0.0f, denScaled = 0.0f;

#pragma unroll
    for (int i = 0; i < ORDER; ++i) {
        float q0 = 0.0f, q1 = 0.0f;
#pragma unroll
        for (int t = 0; t < EPL; t += 2) {
            q0 = fmaf(F[t],     B[t],     q0);
            q1 = fmaf(F[t + 1], B[t + 1], q1);
        }
        float num = rowsum16(q0 + q1);
        if (i > 0) den = denScaled - rowsum16(cpart);
        float r = -2.0f * num * __builtin_amdgcn_rcpf(den);

        // a[:i+2] += r*a[:i+2][::-1]:  a'=a+r*ar ; ar'=(ar+r*a)>>1 lane
        float a_new  = fmaf(r, ar, a);
        float ar_new = fmaf(r, a, ar);
        a  = a_new;
        ar = dppf<0x111>(ar_new);                 // row_shr:1, lane0 <- 0

        float nF[EPL], nB[EPL];
#pragma unroll
        for (int t = 0; t < EPL; ++t) {
            nF[t] = fmaf(r, B[t], F[t]);
            nB[t] = fmaf(r, F[t], B[t]);
        }

        const int pe = 158 - i;                   // compile-time (full unroll)
        const int SL = pe / EPL, SS = pe % EPL;
        float fe = (s == 0)  ? nF[0]  : 0.0f;
        float be = (s == SL) ? nB[SS] : 0.0f;
        cpart = fmaf(fe, fe, be * be);
        denScaled = fmaf(-r * r, den, den);

        float up = dppf<0x101>(nF[0]);            // row_shl:1, lane15 -> 0
#pragma unroll
        for (int t = 0; t < EPL - 1; ++t) F[t] = nF[t + 1];
        F[EPL - 1] = up;
#pragma unroll
        for (int t = 0; t < EPL; ++t) B[t] = nB[t];
        B[SS] = (s == SL) ? 0.0f : B[SS];
    }

    // Broadcast a[0..12] within the group via LDS bounce.
    s_a[wave][g][s] = a;
    __syncthreads();
    float ak[ORDER + 1];
#pragma unroll
    for (int k = 0; k <= ORDER; ++k) ak[k] = s_a[wave][g][k];

    // FIR window straight from padded LDS: Xw[j] = x[p0-12+j], j=0..21
    // (front pad supplies the zero history; no boundary selects).
    float Xw[EPL + ORDER];
#pragma unroll
    for (int j = 0; j < EPL + ORDER; ++j) Xw[j] = Xr[p0 + j];

    const float ac = alpha_p[0] * (2.0f * (float)bits[f_id] - 1.0f);
    float res[EPL];
#pragma unroll
    for (int t = 0; t < EPL; ++t) {
        float acc = 0.0f;
#pragma unroll
        for (int k = 0; k <= ORDER; ++k)
            acc = fmaf(ak[k], Xw[ORDER + t - k], acc);  // res[n]=sum a[k]x[n-k]
        res[t] = fmaf(ac, acc, Xw[ORDER + t]);          // pcm + alpha*res*chip
    }
    float2* og = (float2*)(out + (size_t)f_id * FRAME + p0);
#pragma unroll
    for (int t = 0; t < EPL / 2; ++t)
        og[t] = make_float2(res[2 * t], res[2 * t + 1]);
}

extern "C" void kernel_launch(void* const* d_in, const int* in_sizes, int n_in,
                              void* d_out, int out_size, void* d_ws, size_t ws_size,
                              hipStream_t stream) {
    const int*   bits  = (const int*)d_in[0];
    const float* pcm   = (const float*)d_in[1];
    const float* alpha = (const float*)d_in[2];
    float*       out   = (float*)d_out;

    dim3 grid(NFRAMES / 16), block(256);
    hipLaunchKernelGGL(ResidualEmbedding_70798240907390_kernel, grid, block, 0, stream,
                       bits, pcm, alpha, out);
}